// Round 1
// baseline (2158.078 us; speedup 1.0000x reference)
//
#include <hip/hip_runtime.h>
#include <math.h>

// CVScaledDotProductAttention: complex attention with mag-min-max norm.
// Shapes: [B=8,H=8,S=1024,D=64] fp32. out = stack([real, imag]) -> [2,8,8,1024,64].
//
// Single-pass rewrite (scale-invariant norm):
//   s = (q . k)/8   (complex, no conjugation)
//   out_row = (A - mn*U) / (mx - mn),  A = sum s*v,  U = sum (s/|s|)*v,
//   mn/mx = min/max over k of |s|.

constexpr int S = 1024, D = 64, BH = 64;
constexpr int QT = 32, KT = 32;
constexpr int DP = D + 4;      // padded LDS row (float4-aligned, breaks 512B stride)
constexpr int KP = KT + 1;
constexpr int HALF = BH * S * D;  // 4194304 elements: offset of imag block in out

#define CDOT4(SR, SI, AR, AI, BR, BI)                              \
  SR += AR.x*BR.x + AR.y*BR.y + AR.z*BR.z + AR.w*BR.w              \
      - AI.x*BI.x - AI.y*BI.y - AI.z*BI.z - AI.w*BI.w;             \
  SI += AR.x*BI.x + AR.y*BI.y + AR.z*BI.z + AR.w*BI.w              \
      + AI.x*BR.x + AI.y*BR.y + AI.z*BR.z + AI.w*BR.w;

__global__ __launch_bounds__(256, 2)
void cvattn_kernel(const float* __restrict__ gq_r, const float* __restrict__ gq_i,
                   const float* __restrict__ gk_r, const float* __restrict__ gk_i,
                   const float* __restrict__ gv_r, const float* __restrict__ gv_i,
                   float* __restrict__ gout) {
  __shared__ float qs_r[QT][DP], qs_i[QT][DP];
  __shared__ float ks_r[KT][DP], ks_i[KT][DP];
  __shared__ float vs_r[KT][DP], vs_i[KT][DP];
  __shared__ float sc_r[QT][KP], sc_i[QT][KP], sc_m[QT][KP];

  const int t  = threadIdx.x;
  const int qt = blockIdx.x;   // q-tile index (0..31)
  const int bh = blockIdx.y;   // fused batch*head (0..63)
  const size_t base = (size_t)bh * (S * D);

  // ---- load Q tile [QT][D] (coalesced float4) ----
  {
    const float* qr_p = gq_r + base + (size_t)qt * QT * D;
    const float* qi_p = gq_i + base + (size_t)qt * QT * D;
#pragma unroll
    for (int i = 0; i < 2; ++i) {
      int e = (t + i * 256) * 4;          // element offset in tile (0..2047)
      int row = e >> 6, col = e & 63;
      *(float4*)&qs_r[row][col] = *(const float4*)(qr_p + e);
      *(float4*)&qs_i[row][col] = *(const float4*)(qi_p + e);
    }
  }

  // phase-A identity: 16x16 thread grid, each computes 2q x 2k scores
  const int q0 = (t >> 4) * 2;
  const int k0 = (t & 15) * 2;
  // phase-B identity: 32 rows x 8 chunks of 8 d's
  const int rB = t >> 3;
  const int dc = (t & 7) * 8;

  float Ar[8] = {0,0,0,0,0,0,0,0}, Ai[8] = {0,0,0,0,0,0,0,0};
  float Ur[8] = {0,0,0,0,0,0,0,0}, Ui[8] = {0,0,0,0,0,0,0,0};
  float mn = 3.4e38f, mx = 0.0f;

  for (int kb = 0; kb < S / KT; ++kb) {
    __syncthreads();  // previous phase B done reading ks/vs/sc
    {
      const float* kr_p = gk_r + base + (size_t)kb * KT * D;
      const float* ki_p = gk_i + base + (size_t)kb * KT * D;
      const float* vr_p = gv_r + base + (size_t)kb * KT * D;
      const float* vi_p = gv_i + base + (size_t)kb * KT * D;
#pragma unroll
      for (int i = 0; i < 2; ++i) {
        int e = (t + i * 256) * 4;
        int row = e >> 6, col = e & 63;
        *(float4*)&ks_r[row][col] = *(const float4*)(kr_p + e);
        *(float4*)&ks_i[row][col] = *(const float4*)(ki_p + e);
        *(float4*)&vs_r[row][col] = *(const float4*)(vr_p + e);
        *(float4*)&vs_i[row][col] = *(const float4*)(vi_p + e);
      }
    }
    __syncthreads();

    // ---- phase A: complex QK^T for this tile -> scores in LDS ----
    {
      float s00r=0.f,s00i=0.f,s01r=0.f,s01i=0.f;
      float s10r=0.f,s10i=0.f,s11r=0.f,s11i=0.f;
#pragma unroll
      for (int d = 0; d < D; d += 4) {
        float4 a0r = *(const float4*)&qs_r[q0  ][d];
        float4 a0i = *(const float4*)&qs_i[q0  ][d];
        float4 a1r = *(const float4*)&qs_r[q0+1][d];
        float4 a1i = *(const float4*)&qs_i[q0+1][d];
        float4 b0r = *(const float4*)&ks_r[k0  ][d];
        float4 b0i = *(const float4*)&ks_i[k0  ][d];
        float4 b1r = *(const float4*)&ks_r[k0+1][d];
        float4 b1i = *(const float4*)&ks_i[k0+1][d];
        CDOT4(s00r, s00i, a0r, a0i, b0r, b0i);
        CDOT4(s01r, s01i, a0r, a0i, b1r, b1i);
        CDOT4(s10r, s10i, a1r, a1i, b0r, b0i);
        CDOT4(s11r, s11i, a1r, a1i, b1r, b1i);
      }
      // temperature 8: score = (q.k)/8
      s00r *= 0.125f; s00i *= 0.125f; s01r *= 0.125f; s01i *= 0.125f;
      s10r *= 0.125f; s10i *= 0.125f; s11r *= 0.125f; s11i *= 0.125f;
      sc_r[q0  ][k0  ] = s00r; sc_i[q0  ][k0  ] = s00i;
      sc_m[q0  ][k0  ] = sqrtf(s00r*s00r + s00i*s00i);
      sc_r[q0  ][k0+1] = s01r; sc_i[q0  ][k0+1] = s01i;
      sc_m[q0  ][k0+1] = sqrtf(s01r*s01r + s01i*s01i);
      sc_r[q0+1][k0  ] = s10r; sc_i[q0+1][k0  ] = s10i;
      sc_m[q0+1][k0  ] = sqrtf(s10r*s10r + s10i*s10i);
      sc_r[q0+1][k0+1] = s11r; sc_i[q0+1][k0+1] = s11i;
      sc_m[q0+1][k0+1] = sqrtf(s11r*s11r + s11i*s11i);
    }
    __syncthreads();

    // ---- phase B: dual accumulation A += s*v, U += (s/|s|)*v; track mn/mx ----
#pragma unroll 8
    for (int k = 0; k < KT; ++k) {
      float sr = sc_r[rB][k], si = sc_i[rB][k], mg = sc_m[rB][k];
      mn = fminf(mn, mg);
      mx = fmaxf(mx, mg);
      float inv = 1.0f / mg;
      float ur = sr * inv, ui = si * inv;
      float vr[8], vi[8];
      *(float4*)&vr[0] = *(const float4*)&vs_r[k][dc];
      *(float4*)&vr[4] = *(const float4*)&vs_r[k][dc + 4];
      *(float4*)&vi[0] = *(const float4*)&vs_i[k][dc];
      *(float4*)&vi[4] = *(const float4*)&vs_i[k][dc + 4];
#pragma unroll
      for (int j = 0; j < 8; ++j) {
        Ar[j] += sr * vr[j] - si * vi[j];
        Ai[j] += sr * vi[j] + si * vr[j];
        Ur[j] += ur * vr[j] - ui * vi[j];
        Ui[j] += ur * vi[j] + ui * vr[j];
      }
    }
  }

  // ---- finalize: out = (A - mn*U) / (mx - mn) ----
  float invspan = 1.0f / (mx - mn);
  float outr[8], outi[8];
#pragma unroll
  for (int j = 0; j < 8; ++j) {
    outr[j] = (Ar[j] - mn * Ur[j]) * invspan;
    outi[j] = (Ai[j] - mn * Ui[j]) * invspan;
  }
  size_t o = base + (size_t)(qt * QT + rB) * D + dc;
  *(float4*)(gout + o)            = *(float4*)&outr[0];
  *(float4*)(gout + o + 4)        = *(float4*)&outr[4];
  *(float4*)(gout + HALF + o)     = *(float4*)&outi[0];
  *(float4*)(gout + HALF + o + 4) = *(float4*)&outi[4];
}

extern "C" void kernel_launch(void* const* d_in, const int* in_sizes, int n_in,
                              void* d_out, int out_size, void* d_ws, size_t ws_size,
                              hipStream_t stream) {
  dim3 grid(S / QT, BH);
  cvattn_kernel<<<grid, dim3(256), 0, stream>>>(
      (const float*)d_in[0], (const float*)d_in[1],
      (const float*)d_in[2], (const float*)d_in[3],
      (const float*)d_in[4], (const float*)d_in[5],
      (float*)d_out);
}

// Round 2
// 308.186 us; speedup vs baseline: 7.0025x; 7.0025x over previous
//
#include <hip/hip_runtime.h>
#include <math.h>

typedef unsigned short ushort_t;
typedef __attribute__((ext_vector_type(8))) short short8;   // 8 bf16 = 4 VGPR (MFMA A/B frag)
typedef __attribute__((ext_vector_type(4))) float f32x4;    // MFMA C/D frag
typedef __attribute__((ext_vector_type(4))) int int4v;
typedef __attribute__((ext_vector_type(4))) unsigned short ushort4v;

constexpr int S = 1024, D = 64, BH = 64;
constexpr int HALF = BH * S * D;          // imag offset in output
constexpr int KROW = 72;                  // padded bf16 row for K/Q tiles (144B, 2-way banks)
constexpr int VROW = 40;                  // padded bf16 row for V^T tiles (80B, 2-way banks)
constexpr int TILE_USH = 2 * 32 * KROW + 2 * 64 * VROW;  // 9728 ushorts = 19456 B per (bh,kb)
constexpr size_t WS_NEED = (size_t)BH * 32 * TILE_USH * 2;  // ~39.8 MB

#define MFMA16(a, b, c) __builtin_amdgcn_mfma_f32_16x16x32_bf16(a, b, c, 0, 0, 0)

__device__ __forceinline__ ushort_t f2bf(float f) {  // RNE fp32->bf16
  unsigned u = __float_as_uint(f);
  u += 0x7fff + ((u >> 16) & 1);
  return (ushort_t)(u >> 16);
}

// ---------------- prepass: K,V -> bf16, V transposed, padded MFMA-friendly ws tiles ---------
__global__ __launch_bounds__(256)
void prepass_kernel(const float* __restrict__ kr, const float* __restrict__ ki,
                    const float* __restrict__ vr, const float* __restrict__ vi,
                    ushort_t* __restrict__ ws) {
  __shared__ ushort_t tmp[32 * KROW];
  const int t = threadIdx.x;
  const int tile = blockIdx.x;                    // bh*32 + kb
  const size_t gbase = (size_t)tile * (32 * D);   // contiguous 32-row chunks
  ushort_t* wst = ws + (size_t)tile * TILE_USH;

  const int k = t >> 3, d0 = (t & 7) * 8;
  const float* kp[2] = {kr, ki};
#pragma unroll
  for (int c = 0; c < 2; ++c) {
    const float* src = kp[c] + gbase + k * D + d0;
    float4 a = *(const float4*)src;
    float4 b = *(const float4*)(src + 4);
    ushort4v w0 = {f2bf(a.x), f2bf(a.y), f2bf(a.z), f2bf(a.w)};
    ushort4v w1 = {f2bf(b.x), f2bf(b.y), f2bf(b.z), f2bf(b.w)};
    ushort_t* dst = wst + c * (32 * KROW) + k * KROW + d0;
    *(ushort4v*)dst = w0;
    *(ushort4v*)(dst + 4) = w1;
  }
  const float* vp[2] = {vr, vi};
  for (int c = 0; c < 2; ++c) {
    if (c) __syncthreads();
    {
      const float* src = vp[c] + gbase + k * D + d0;
      float4 a = *(const float4*)src;
      float4 b = *(const float4*)(src + 4);
      ushort4v w0 = {f2bf(a.x), f2bf(a.y), f2bf(a.z), f2bf(a.w)};
      ushort4v w1 = {f2bf(b.x), f2bf(b.y), f2bf(b.z), f2bf(b.w)};
      *(ushort4v*)&tmp[k * KROW + d0] = w0;
      *(ushort4v*)&tmp[k * KROW + d0 + 4] = w1;
    }
    __syncthreads();
    const int d = t >> 2, k0 = (t & 3) * 8;
    ushort4v o0 = {tmp[(k0 + 0) * KROW + d], tmp[(k0 + 1) * KROW + d],
                   tmp[(k0 + 2) * KROW + d], tmp[(k0 + 3) * KROW + d]};
    ushort4v o1 = {tmp[(k0 + 4) * KROW + d], tmp[(k0 + 5) * KROW + d],
                   tmp[(k0 + 6) * KROW + d], tmp[(k0 + 7) * KROW + d]};
    ushort_t* dst = wst + 2 * (32 * KROW) + c * (64 * VROW) + d * VROW + k0;
    *(ushort4v*)dst = o0;
    *(ushort4v*)(dst + 4) = o1;
  }
}

// ---------------- main MFMA kernel: 64 q-rows/block, 4 waves x 16 q-rows -------------------
__global__ __launch_bounds__(256, 2)
void cvattn_mfma(const float* __restrict__ gq_r, const float* __restrict__ gq_i,
                 const ushort_t* __restrict__ ws, float* __restrict__ gout) {
  // LDS map (bytes): [0,19456) staged K/V tile (mirrors ws tile layout exactly);
  // [19456, 39936): per-wave P buffers, overlaid with Q staging (used once, before loop).
  __shared__ __attribute__((aligned(16))) char smem[39936];
  ushort_t* sB = (ushort_t*)smem;        // Kr@0, Ki@2304, Vtr@4608, Vti@7168 (ushort offs)
  ushort_t* sP = (ushort_t*)(smem + 19456);
  ushort_t* sQ = (ushort_t*)(smem + 19456);  // overlay: Qr[64][72], Qi after

  const int t = threadIdx.x;
  const int lane = t & 63, wave = t >> 6;
  const int m = lane & 15, quad = lane >> 4;
  const int qt = blockIdx.x, bh = blockIdx.y;
  const size_t base = (size_t)bh * (S * D);

  // ---- stage Q (fp32 -> bf16 LDS, once) ----
  {
    const float* qr = gq_r + base + (size_t)qt * (64 * D);
    const float* qi = gq_i + base + (size_t)qt * (64 * D);
#pragma unroll
    for (int i = 0; i < 4; ++i) {
      int e = (i * 256 + t) * 4;
      int q = e >> 6, d = e & 63;
      float4 a = *(const float4*)(qr + e);
      float4 b = *(const float4*)(qi + e);
      ushort4v wa = {f2bf(a.x), f2bf(a.y), f2bf(a.z), f2bf(a.w)};
      ushort4v wb = {f2bf(b.x), f2bf(b.y), f2bf(b.z), f2bf(b.w)};
      *(ushort4v*)&sQ[q * KROW + d] = wa;
      *(ushort4v*)&sQ[64 * KROW + q * KROW + d] = wb;
    }
  }
  __syncthreads();

  // ---- hoist Q A-frags (row m = q, k = quad*8+j) ----
  short8 fQr[2], fQi[2], fQin[2];
  {
    const int qrow = wave * 16 + m;
#pragma unroll
    for (int dc = 0; dc < 2; ++dc) {
      fQr[dc] = *(const short8*)&sQ[qrow * KROW + dc * 32 + quad * 8];
      fQi[dc] = *(const short8*)&sQ[64 * KROW + qrow * KROW + dc * 32 + quad * 8];
      fQin[dc] = fQi[dc] ^ (short)0x8000;  // -Qi (bf16 sign flip)
    }
  }

  f32x4 aAr[4] = {}, aAi[4] = {}, aUr[4] = {}, aUi[4] = {};
  float mn4[4] = {1e30f, 1e30f, 1e30f, 1e30f};
  float mx4[4] = {0.f, 0.f, 0.f, 0.f};

  ushort_t* pw = sP + wave * 2560;  // pr@0, pi@640, ur@1280, ui@1920
  const ushort_t* wsrc = ws + (size_t)bh * 32 * TILE_USH;

  for (int kb = 0; kb < 32; ++kb) {
    __syncthreads();  // prev iter's K/V reads done (also: Q-frag reads done before P stores)
    {
      const ushort_t* g = wsrc + (size_t)kb * TILE_USH;
#pragma unroll
      for (int i = 0; i < 5; ++i) {
        int idx = i * 256 + t;
        if (idx < 1216)  // 19456 B / 16
          *(int4v*)(smem + idx * 16) = *(const int4v*)(g + idx * 8);
      }
    }
    __syncthreads();

    // ---- QK^T (complex) -> normalize -> P/U to LDS ----
#pragma unroll
    for (int ks = 0; ks < 2; ++ks) {
      const int krow = ks * 16 + m;
      short8 fKr0 = *(const short8*)&sB[krow * KROW + quad * 8];
      short8 fKr1 = *(const short8*)&sB[krow * KROW + 32 + quad * 8];
      short8 fKi0 = *(const short8*)&sB[2304 + krow * KROW + quad * 8];
      short8 fKi1 = *(const short8*)&sB[2304 + krow * KROW + 32 + quad * 8];
      f32x4 cSr = {}, cSi = {};
      cSr = MFMA16(fQr[0], fKr0, cSr);
      cSr = MFMA16(fQr[1], fKr1, cSr);
      cSr = MFMA16(fQin[0], fKi0, cSr);   // - Qi*Ki
      cSr = MFMA16(fQin[1], fKi1, cSr);
      cSi = MFMA16(fQr[0], fKi0, cSi);
      cSi = MFMA16(fQr[1], fKi1, cSi);
      cSi = MFMA16(fQi[0], fKr0, cSi);
      cSi = MFMA16(fQi[1], fKr1, cSi);
      // temperature /8 cancels in the min-max norm (power of 2: bf16 rounding identical)
#pragma unroll
      for (int r = 0; r < 4; ++r) {
        float sr = cSr[r], si = cSi[r];
        float t2 = sr * sr + si * si;
        float rq = __builtin_amdgcn_rsqf(t2);
        float mag = t2 * rq;
        mn4[r] = fminf(mn4[r], mag);
        mx4[r] = fmaxf(mx4[r], mag);
        const int off = (quad * 4 + r) * VROW + ks * 16 + m;  // C-layout -> A-layout via LDS
        pw[off] = f2bf(sr);
        pw[640 + off] = f2bf(si);
        pw[1280 + off] = f2bf(sr * rq);   // unit phase
        pw[1920 + off] = f2bf(si * rq);
      }
    }

    // ---- dual PV: A += s*v, U += u*v (complex) ----
    short8 fPr = *(const short8*)&pw[m * VROW + quad * 8];
    short8 fPi = *(const short8*)&pw[640 + m * VROW + quad * 8];
    short8 fUr = *(const short8*)&pw[1280 + m * VROW + quad * 8];
    short8 fUi = *(const short8*)&pw[1920 + m * VROW + quad * 8];
#pragma unroll
    for (int dt = 0; dt < 4; ++dt) {
      const int drow = dt * 16 + m;
      short8 fVr = *(const short8*)&sB[4608 + drow * VROW + quad * 8];
      short8 fVi = *(const short8*)&sB[7168 + drow * VROW + quad * 8];
      short8 fVin = fVi ^ (short)0x8000;
      aAr[dt] = MFMA16(fPr, fVr, aAr[dt]);
      aAr[dt] = MFMA16(fPi, fVin, aAr[dt]);
      aAi[dt] = MFMA16(fPr, fVi, aAi[dt]);
      aAi[dt] = MFMA16(fPi, fVr, aAi[dt]);
      aUr[dt] = MFMA16(fUr, fVr, aUr[dt]);
      aUr[dt] = MFMA16(fUi, fVin, aUr[dt]);
      aUi[dt] = MFMA16(fUr, fVi, aUi[dt]);
      aUi[dt] = MFMA16(fUi, fVr, aUi[dt]);
    }
  }

  // ---- reduce mn/mx across the 16 lanes sharing each q-row ----
#pragma unroll
  for (int r = 0; r < 4; ++r) {
#pragma unroll
    for (int mask = 1; mask < 16; mask <<= 1) {
      mn4[r] = fminf(mn4[r], __shfl_xor(mn4[r], mask, 64));
      mx4[r] = fmaxf(mx4[r], __shfl_xor(mx4[r], mask, 64));
    }
  }
  float inv[4];
#pragma unroll
  for (int r = 0; r < 4; ++r) inv[r] = 1.0f / (mx4[r] - mn4[r]);

  // ---- epilogue: out = (A - mn*U) / (mx - mn) ----
  const int qbase = qt * 64 + wave * 16 + quad * 4;
#pragma unroll
  for (int dt = 0; dt < 4; ++dt) {
    const int d = dt * 16 + m;
#pragma unroll
    for (int r = 0; r < 4; ++r) {
      size_t o = base + (size_t)(qbase + r) * D + d;
      gout[o] = (aAr[dt][r] - mn4[r] * aUr[dt][r]) * inv[r];
      gout[HALF + o] = (aAi[dt][r] - mn4[r] * aUi[dt][r]) * inv[r];
    }
  }
}

// ---------------- fp32 fallback (round-1 kernel, used only if ws too small) ----------------
constexpr int QT = 32, KT = 32;
constexpr int DP = D + 4;
constexpr int KP = KT + 1;

#define CDOT4(SR, SI, AR, AI, BR, BI)                              \
  SR += AR.x*BR.x + AR.y*BR.y + AR.z*BR.z + AR.w*BR.w              \
      - AI.x*BI.x - AI.y*BI.y - AI.z*BI.z - AI.w*BI.w;             \
  SI += AR.x*BI.x + AR.y*BI.y + AR.z*BI.z + AR.w*BI.w              \
      + AI.x*BR.x + AI.y*BR.y + AI.z*BR.z + AI.w*BR.w;

__global__ __launch_bounds__(256, 2)
void cvattn_fallback(const float* __restrict__ gq_r, const float* __restrict__ gq_i,
                     const float* __restrict__ gk_r, const float* __restrict__ gk_i,
                     const float* __restrict__ gv_r, const float* __restrict__ gv_i,
                     float* __restrict__ gout) {
  __shared__ float qs_r[QT][DP], qs_i[QT][DP];
  __shared__ float ks_r[KT][DP], ks_i[KT][DP];
  __shared__ float vs_r[KT][DP], vs_i[KT][DP];
  __shared__ float sc_r[QT][KP], sc_i[QT][KP], sc_m[QT][KP];
  const int t = threadIdx.x;
  const int qt2 = blockIdx.x, bh = blockIdx.y;
  const size_t base = (size_t)bh * (S * D);
  {
    const float* qr_p = gq_r + base + (size_t)qt2 * QT * D;
    const float* qi_p = gq_i + base + (size_t)qt2 * QT * D;
#pragma unroll
    for (int i = 0; i < 2; ++i) {
      int e = (t + i * 256) * 4;
      int row = e >> 6, col = e & 63;
      *(float4*)&qs_r[row][col] = *(const float4*)(qr_p + e);
      *(float4*)&qs_i[row][col] = *(const float4*)(qi_p + e);
    }
  }
  const int q0 = (t >> 4) * 2, k0 = (t & 15) * 2;
  const int rB = t >> 3, dc = (t & 7) * 8;
  float Ar[8] = {}, Ai[8] = {}, Ur[8] = {}, Ui[8] = {};
  float mn = 3.4e38f, mx = 0.0f;
  for (int kb = 0; kb < S / KT; ++kb) {
    __syncthreads();
    {
      const float* kr_p = gk_r + base + (size_t)kb * KT * D;
      const float* ki_p = gk_i + base + (size_t)kb * KT * D;
      const float* vr_p = gv_r + base + (size_t)kb * KT * D;
      const float* vi_p = gv_i + base + (size_t)kb * KT * D;
#pragma unroll
      for (int i = 0; i < 2; ++i) {
        int e = (t + i * 256) * 4;
        int row = e >> 6, col = e & 63;
        *(float4*)&ks_r[row][col] = *(const float4*)(kr_p + e);
        *(float4*)&ks_i[row][col] = *(const float4*)(ki_p + e);
        *(float4*)&vs_r[row][col] = *(const float4*)(vr_p + e);
        *(float4*)&vs_i[row][col] = *(const float4*)(vi_p + e);
      }
    }
    __syncthreads();
    {
      float s00r=0.f,s00i=0.f,s01r=0.f,s01i=0.f;
      float s10r=0.f,s10i=0.f,s11r=0.f,s11i=0.f;
#pragma unroll
      for (int d = 0; d < D; d += 4) {
        float4 a0r = *(const float4*)&qs_r[q0  ][d];
        float4 a0i = *(const float4*)&qs_i[q0  ][d];
        float4 a1r = *(const float4*)&qs_r[q0+1][d];
        float4 a1i = *(const float4*)&qs_i[q0+1][d];
        float4 b0r = *(const float4*)&ks_r[k0  ][d];
        float4 b0i = *(const float4*)&ks_i[k0  ][d];
        float4 b1r = *(const float4*)&ks_r[k0+1][d];
        float4 b1i = *(const float4*)&ks_i[k0+1][d];
        CDOT4(s00r, s00i, a0r, a0i, b0r, b0i);
        CDOT4(s01r, s01i, a0r, a0i, b1r, b1i);
        CDOT4(s10r, s10i, a1r, a1i, b0r, b0i);
        CDOT4(s11r, s11i, a1r, a1i, b1r, b1i);
      }
      s00r *= 0.125f; s00i *= 0.125f; s01r *= 0.125f; s01i *= 0.125f;
      s10r *= 0.125f; s10i *= 0.125f; s11r *= 0.125f; s11i *= 0.125f;
      sc_r[q0  ][k0  ] = s00r; sc_i[q0  ][k0  ] = s00i;
      sc_m[q0  ][k0  ] = sqrtf(s00r*s00r + s00i*s00i);
      sc_r[q0  ][k0+1] = s01r; sc_i[q0  ][k0+1] = s01i;
      sc_m[q0  ][k0+1] = sqrtf(s01r*s01r + s01i*s01i);
      sc_r[q0+1][k0  ] = s10r; sc_i[q0+1][k0  ] = s10i;
      sc_m[q0+1][k0  ] = sqrtf(s10r*s10r + s10i*s10i);
      sc_r[q0+1][k0+1] = s11r; sc_i[q0+1][k0+1] = s11i;
      sc_m[q0+1][k0+1] = sqrtf(s11r*s11r + s11i*s11i);
    }
    __syncthreads();
#pragma unroll 8
    for (int k = 0; k < KT; ++k) {
      float sr = sc_r[rB][k], si = sc_i[rB][k], mg = sc_m[rB][k];
      mn = fminf(mn, mg); mx = fmaxf(mx, mg);
      float inv = 1.0f / mg;
      float ur = sr * inv, ui = si * inv;
      float vr[8], vi[8];
      *(float4*)&vr[0] = *(const float4*)&vs_r[k][dc];
      *(float4*)&vr[4] = *(const float4*)&vs_r[k][dc + 4];
      *(float4*)&vi[0] = *(const float4*)&vs_i[k][dc];
      *(float4*)&vi[4] = *(const float4*)&vs_i[k][dc + 4];
#pragma unroll
      for (int j = 0; j < 8; ++j) {
        Ar[j] += sr * vr[j] - si * vi[j];
        Ai[j] += sr * vi[j] + si * vr[j];
        Ur[j] += ur * vr[j] - ui * vi[j];
        Ui[j] += ur * vi[j] + ui * vr[j];
      }
    }
  }
  float invspan = 1.0f / (mx - mn);
  float outr[8], outi[8];
#pragma unroll
  for (int j = 0; j < 8; ++j) {
    outr[j] = (Ar[j] - mn * Ur[j]) * invspan;
    outi[j] = (Ai[j] - mn * Ui[j]) * invspan;
  }
  size_t o = base + (size_t)(qt2 * QT + rB) * D + dc;
  *(float4*)(gout + o)            = *(float4*)&outr[0];
  *(float4*)(gout + o + 4)        = *(float4*)&outr[4];
  *(float4*)(gout + HALF + o)     = *(float4*)&outi[0];
  *(float4*)(gout + HALF + o + 4) = *(float4*)&outi[4];
}

extern "C" void kernel_launch(void* const* d_in, const int* in_sizes, int n_in,
                              void* d_out, int out_size, void* d_ws, size_t ws_size,
                              hipStream_t stream) {
  if (ws_size >= WS_NEED) {
    prepass_kernel<<<dim3(BH * 32), 256, 0, stream>>>(
        (const float*)d_in[2], (const float*)d_in[3],
        (const float*)d_in[4], (const float*)d_in[5], (ushort_t*)d_ws);
    cvattn_mfma<<<dim3(S / 64, BH), 256, 0, stream>>>(
        (const float*)d_in[0], (const float*)d_in[1],
        (const ushort_t*)d_ws, (float*)d_out);
  } else {
    cvattn_fallback<<<dim3(S / QT, BH), 256, 0, stream>>>(
        (const float*)d_in[0], (const float*)d_in[1],
        (const float*)d_in[2], (const float*)d_in[3],
        (const float*)d_in[4], (const float*)d_in[5], (float*)d_out);
  }
}

// Round 3
// 263.625 us; speedup vs baseline: 8.1862x; 1.1690x over previous
//
#include <hip/hip_runtime.h>
#include <math.h>

typedef unsigned short ushort_t;
typedef __attribute__((ext_vector_type(8))) short short8;   // 8 bf16 = 4 VGPR (MFMA A/B frag)
typedef __attribute__((ext_vector_type(4))) float f32x4;    // MFMA C/D frag
typedef __attribute__((ext_vector_type(4))) int int4v;
typedef __attribute__((ext_vector_type(4))) unsigned short ushort4v;

constexpr int S = 1024, D = 64, BH = 64;
constexpr int HALF = BH * S * D;          // imag offset in output
constexpr int KROW = 72;                  // bf16 row stride for K/Q tiles (36 dw: even granule spread)
constexpr int VROW = 40;                  // bf16 row stride for V^T / P tiles (20 dw: even granule spread)
constexpr int TILE_USH = 2 * 32 * KROW + 2 * 64 * VROW;  // 9728 ushorts = 19456 B per (bh,kb)
constexpr size_t WS_NEED = (size_t)BH * 32 * TILE_USH * 2;  // ~39.8 MB

#define MFMA16(a, b, c) __builtin_amdgcn_mfma_f32_16x16x32_bf16(a, b, c, 0, 0, 0)

__device__ __forceinline__ ushort_t f2bf(float f) {  // RNE fp32->bf16
  unsigned u = __float_as_uint(f);
  u += 0x7fff + ((u >> 16) & 1);
  return (ushort_t)(u >> 16);
}

// ---------------- prepass: K,V -> bf16, V transposed via fp32 LDS (stride 65: 2-way banks) ----
__global__ __launch_bounds__(256)
void prepass_kernel(const float* __restrict__ kr, const float* __restrict__ ki,
                    const float* __restrict__ vr, const float* __restrict__ vi,
                    ushort_t* __restrict__ ws) {
  __shared__ float tmp2[32 * 65];                  // 8320 B; bank = (k + d) % 32
  const int t = threadIdx.x;
  const int tile = blockIdx.x;                    // bh*32 + kb
  const size_t gbase = (size_t)tile * (32 * D);   // contiguous 32-row chunks
  ushort_t* wst = ws + (size_t)tile * TILE_USH;

  const int k = t >> 3, d0 = (t & 7) * 8;
  // ---- K channels: straight row-major bf16 ----
  {
    const float* kp[2] = {kr, ki};
#pragma unroll
    for (int c = 0; c < 2; ++c) {
      const float* src = kp[c] + gbase + k * D + d0;
      float4 a = *(const float4*)src;
      float4 b = *(const float4*)(src + 4);
      ushort4v w0 = {f2bf(a.x), f2bf(a.y), f2bf(a.z), f2bf(a.w)};
      ushort4v w1 = {f2bf(b.x), f2bf(b.y), f2bf(b.z), f2bf(b.w)};
      ushort_t* dst = wst + c * (32 * KROW) + k * KROW + d0;
      *(ushort4v*)dst = w0;
      *(ushort4v*)(dst + 4) = w1;
    }
  }
  // ---- V channels: transpose through fp32 LDS ----
  const float* vp[2] = {vr, vi};
  for (int c = 0; c < 2; ++c) {
    if (c) __syncthreads();   // prev channel's reads done
    {
      const float* src = vp[c] + gbase + k * D + d0;
      float4 a = *(const float4*)src;
      float4 b = *(const float4*)(src + 4);
      *(float4*)&tmp2[k * 65 + d0] = a;        // bank=(k+d0)%32: 2-way, free
      *(float4*)&tmp2[k * 65 + d0 + 4] = b;
    }
    __syncthreads();
    const int d = t >> 2, k0 = (t & 3) * 8;
    float v[8];
#pragma unroll
    for (int j = 0; j < 8; ++j) v[j] = tmp2[(k0 + j) * 65 + d];  // bank=(k0+j+d)%32: 2-way
    ushort4v o0 = {f2bf(v[0]), f2bf(v[1]), f2bf(v[2]), f2bf(v[3])};
    ushort4v o1 = {f2bf(v[4]), f2bf(v[5]), f2bf(v[6]), f2bf(v[7])};
    ushort_t* dst = wst + 2 * (32 * KROW) + c * (64 * VROW) + d * VROW + k0;
    *(ushort4v*)dst = o0;
    *(ushort4v*)(dst + 4) = o1;
  }
}

// ---------------- main MFMA kernel: 64 q-rows/block, 4 waves x 16 q-rows -------------------
__global__ __launch_bounds__(256, 2)
void cvattn_mfma(const float* __restrict__ gq_r, const float* __restrict__ gq_i,
                 const ushort_t* __restrict__ ws, float* __restrict__ gout) {
  // LDS map (bytes): [0,19456) staged K/V tile (mirrors ws tile layout exactly);
  // [19456, 39936): per-wave P buffers, overlaid with Q staging (used once, before loop).
  __shared__ __attribute__((aligned(16))) char smem[39936];
  ushort_t* sB = (ushort_t*)smem;        // Kr@0, Ki@2304, Vtr@4608, Vti@7168 (ushort offs)
  ushort_t* sP = (ushort_t*)(smem + 19456);
  ushort_t* sQ = (ushort_t*)(smem + 19456);  // overlay: Qr[64][72], Qi after

  const int t = threadIdx.x;
  const int lane = t & 63, wave = t >> 6;
  const int m = lane & 15, quad = lane >> 4;
  const int qt = blockIdx.x, bh = blockIdx.y;
  const size_t base = (size_t)bh * (S * D);

  // ---- stage Q (fp32 -> bf16 LDS, once) ----
  {
    const float* qr = gq_r + base + (size_t)qt * (64 * D);
    const float* qi = gq_i + base + (size_t)qt * (64 * D);
#pragma unroll
    for (int i = 0; i < 4; ++i) {
      int e = (i * 256 + t) * 4;
      int q = e >> 6, d = e & 63;
      float4 a = *(const float4*)(qr + e);
      float4 b = *(const float4*)(qi + e);
      ushort4v wa = {f2bf(a.x), f2bf(a.y), f2bf(a.z), f2bf(a.w)};
      ushort4v wb = {f2bf(b.x), f2bf(b.y), f2bf(b.z), f2bf(b.w)};
      *(ushort4v*)&sQ[q * KROW + d] = wa;
      *(ushort4v*)&sQ[64 * KROW + q * KROW + d] = wb;
    }
  }
  __syncthreads();

  // ---- hoist Q A-frags (row m = q, k = quad*8+j) ----
  short8 fQr[2], fQi[2], fQin[2];
  {
    const int qrow = wave * 16 + m;
#pragma unroll
    for (int dc = 0; dc < 2; ++dc) {
      fQr[dc] = *(const short8*)&sQ[qrow * KROW + dc * 32 + quad * 8];
      fQi[dc] = *(const short8*)&sQ[64 * KROW + qrow * KROW + dc * 32 + quad * 8];
      fQin[dc] = fQi[dc] ^ (short)0x8000;  // -Qi (bf16 sign flip)
    }
  }

  f32x4 aAr[4] = {}, aAi[4] = {}, aUr[4] = {}, aUi[4] = {};
  float mn4[4] = {1e30f, 1e30f, 1e30f, 1e30f};   // track |s|^2 (sqrt at end)
  float mx4[4] = {0.f, 0.f, 0.f, 0.f};

  ushort_t* pw = sP + wave * 2560;  // pr@0, pi@640, ur@1280, ui@1920
  const ushort_t* wsrc = ws + (size_t)bh * 32 * TILE_USH;

  // ---- register prefetch of tile kb=0 ----
  int4v pre[5];
#pragma unroll
  for (int i = 0; i < 5; ++i) {
    int idx = i * 256 + t;
    if (idx < 1216) pre[i] = *(const int4v*)(wsrc + idx * 8);
  }

  for (int kb = 0; kb < 32; ++kb) {
    __syncthreads();  // prev iter's LDS reads done (also covers Q-frag reads vs P overlay)
    // write prefetched tile to LDS
#pragma unroll
    for (int i = 0; i < 5; ++i) {
      int idx = i * 256 + t;
      if (idx < 1216) *(int4v*)(smem + idx * 16) = pre[i];
    }
    // issue next tile's global loads — they fly during the whole compute phase
    if (kb + 1 < 32) {
      const ushort_t* g = wsrc + (size_t)(kb + 1) * TILE_USH;
#pragma unroll
      for (int i = 0; i < 5; ++i) {
        int idx = i * 256 + t;
        if (idx < 1216) pre[i] = *(const int4v*)(g + idx * 8);
      }
    }
    __syncthreads();

    // ---- QK^T (complex) -> normalize -> P/U to LDS (XOR-granule swizzled) ----
#pragma unroll
    for (int ks = 0; ks < 2; ++ks) {
      const int krow = ks * 16 + m;
      short8 fKr0 = *(const short8*)&sB[krow * KROW + quad * 8];
      short8 fKr1 = *(const short8*)&sB[krow * KROW + 32 + quad * 8];
      short8 fKi0 = *(const short8*)&sB[2304 + krow * KROW + quad * 8];
      short8 fKi1 = *(const short8*)&sB[2304 + krow * KROW + 32 + quad * 8];
      f32x4 cSr = {}, cSi = {};
      cSr = MFMA16(fQr[0], fKr0, cSr);
      cSr = MFMA16(fQr[1], fKr1, cSr);
      cSr = MFMA16(fQin[0], fKi0, cSr);   // - Qi*Ki
      cSr = MFMA16(fQin[1], fKi1, cSr);
      cSi = MFMA16(fQr[0], fKi0, cSi);
      cSi = MFMA16(fQr[1], fKi1, cSi);
      cSi = MFMA16(fQi[0], fKr0, cSi);
      cSi = MFMA16(fQi[1], fKr1, cSi);
      // temperature /8 cancels in the min-max norm (power of 2: bf16 rounding identical)
      // swizzle: logical col granule gc = (ks*16+m)>>3; phys = gc ^ (row>>2), row>>2 == quad
      const int pcol = ((ks * 2 + (m >> 3)) ^ quad) * 8 + (m & 7);
#pragma unroll
      for (int r = 0; r < 4; ++r) {
        float sr = cSr[r], si = cSi[r];
        float t2 = sr * sr + si * si;
        float rq = __builtin_amdgcn_rsqf(t2);
        mn4[r] = fminf(mn4[r], t2);
        mx4[r] = fmaxf(mx4[r], t2);
        const int off = (quad * 4 + r) * VROW + pcol;  // write banks: full 2-way spread
        pw[off] = f2bf(sr);
        pw[640 + off] = f2bf(si);
        pw[1280 + off] = f2bf(sr * rq);   // unit phase
        pw[1920 + off] = f2bf(si * rq);
      }
    }

    // ---- dual PV: A += s*v, U += u*v (complex) ----
    const int prow = m * VROW + ((quad ^ (m >> 2)) * 8);  // same swizzle, granule-aligned b128
    short8 fPr = *(const short8*)&pw[prow];
    short8 fPi = *(const short8*)&pw[640 + prow];
    short8 fUr = *(const short8*)&pw[1280 + prow];
    short8 fUi = *(const short8*)&pw[1920 + prow];
#pragma unroll
    for (int dt = 0; dt < 4; ++dt) {
      const int drow = dt * 16 + m;
      short8 fVr = *(const short8*)&sB[4608 + drow * VROW + quad * 8];
      short8 fVi = *(const short8*)&sB[7168 + drow * VROW + quad * 8];
      short8 fVin = fVi ^ (short)0x8000;
      aAr[dt] = MFMA16(fPr, fVr, aAr[dt]);
      aAr[dt] = MFMA16(fPi, fVin, aAr[dt]);
      aAi[dt] = MFMA16(fPr, fVi, aAi[dt]);
      aAi[dt] = MFMA16(fPi, fVr, aAi[dt]);
      aUr[dt] = MFMA16(fUr, fVr, aUr[dt]);
      aUr[dt] = MFMA16(fUi, fVin, aUr[dt]);
      aUi[dt] = MFMA16(fUr, fVi, aUi[dt]);
      aUi[dt] = MFMA16(fUi, fVr, aUi[dt]);
    }
  }

  // ---- reduce mn/mx (of |s|^2) across the 16 lanes sharing each q-row ----
#pragma unroll
  for (int r = 0; r < 4; ++r) {
#pragma unroll
    for (int mask = 1; mask < 16; mask <<= 1) {
      mn4[r] = fminf(mn4[r], __shfl_xor(mn4[r], mask, 64));
      mx4[r] = fmaxf(mx4[r], __shfl_xor(mx4[r], mask, 64));
    }
  }
  float inv[4];
#pragma unroll
  for (int r = 0; r < 4; ++r) {
    mn4[r] = sqrtf(mn4[r]);
    mx4[r] = sqrtf(mx4[r]);
    inv[r] = 1.0f / (mx4[r] - mn4[r]);
  }

  // ---- epilogue: out = (A - mn*U) / (mx - mn) ----
  const int qbase = qt * 64 + wave * 16 + quad * 4;
#pragma unroll
  for (int dt = 0; dt < 4; ++dt) {
    const int d = dt * 16 + m;
#pragma unroll
    for (int r = 0; r < 4; ++r) {
      size_t o = base + (size_t)(qbase + r) * D + d;
      gout[o] = (aAr[dt][r] - mn4[r] * aUr[dt][r]) * inv[r];
      gout[HALF + o] = (aAi[dt][r] - mn4[r] * aUi[dt][r]) * inv[r];
    }
  }
}

// ---------------- fp32 fallback (round-1 kernel, used only if ws too small) ----------------
constexpr int QT = 32, KT = 32;
constexpr int DP = D + 4;
constexpr int KP = KT + 1;

#define CDOT4(SR, SI, AR, AI, BR, BI)                              \
  SR += AR.x*BR.x + AR.y*BR.y + AR.z*BR.z + AR.w*BR.w              \
      - AI.x*BI.x - AI.y*BI.y - AI.z*BI.z - AI.w*BI.w;             \
  SI += AR.x*BI.x + AR.y*BI.y + AR.z*BI.z + AR.w*BI.w              \
      + AI.x*BR.x + AI.y*BR.y + AI.z*BR.z + AI.w*BR.w;

__global__ __launch_bounds__(256, 2)
void cvattn_fallback(const float* __restrict__ gq_r, const float* __restrict__ gq_i,
                     const float* __restrict__ gk_r, const float* __restrict__ gk_i,
                     const float* __restrict__ gv_r, const float* __restrict__ gv_i,
                     float* __restrict__ gout) {
  __shared__ float qs_r[QT][DP], qs_i[QT][DP];
  __shared__ float ks_r[KT][DP], ks_i[KT][DP];
  __shared__ float vs_r[KT][DP], vs_i[KT][DP];
  __shared__ float sc_r[QT][KP], sc_i[QT][KP], sc_m[QT][KP];
  const int t = threadIdx.x;
  const int qt2 = blockIdx.x, bh = blockIdx.y;
  const size_t base = (size_t)bh * (S * D);
  {
    const float* qr_p = gq_r + base + (size_t)qt2 * QT * D;
    const float* qi_p = gq_i + base + (size_t)qt2 * QT * D;
#pragma unroll
    for (int i = 0; i < 2; ++i) {
      int e = (t + i * 256) * 4;
      int row = e >> 6, col = e & 63;
      *(float4*)&qs_r[row][col] = *(const float4*)(qr_p + e);
      *(float4*)&qs_i[row][col] = *(const float4*)(qi_p + e);
    }
  }
  const int q0 = (t >> 4) * 2, k0 = (t & 15) * 2;
  const int rB = t >> 3, dc = (t & 7) * 8;
  float Ar[8] = {}, Ai[8] = {}, Ur[8] = {}, Ui[8] = {};
  float mn = 3.4e38f, mx = 0.0f;
  for (int kb = 0; kb < S / KT; ++kb) {
    __syncthreads();
    {
      const float* kr_p = gk_r + base + (size_t)kb * KT * D;
      const float* ki_p = gk_i + base + (size_t)kb * KT * D;
      const float* vr_p = gv_r + base + (size_t)kb * KT * D;
      const float* vi_p = gv_i + base + (size_t)kb * KT * D;
#pragma unroll
    for (int i = 0; i < 2; ++i) {
        int e = (t + i * 256) * 4;
        int row = e >> 6, col = e & 63;
        *(float4*)&ks_r[row][col] = *(const float4*)(kr_p + e);
        *(float4*)&ks_i[row][col] = *(const float4*)(ki_p + e);
        *(float4*)&vs_r[row][col] = *(const float4*)(vr_p + e);
        *(float4*)&vs_i[row][col] = *(const float4*)(vi_p + e);
      }
    }
    __syncthreads();
    {
      float s00r=0.f,s00i=0.f,s01r=0.f,s01i=0.f;
      float s10r=0.f,s10i=0.f,s11r=0.f,s11i=0.f;
#pragma unroll
      for (int d = 0; d < D; d += 4) {
        float4 a0r = *(const float4*)&qs_r[q0  ][d];
        float4 a0i = *(const float4*)&qs_i[q0  ][d];
        float4 a1r = *(const float4*)&qs_r[q0+1][d];
        float4 a1i = *(const float4*)&qs_i[q0+1][d];
        float4 b0r = *(const float4*)&ks_r[k0  ][d];
        float4 b0i = *(const float4*)&ks_i[k0  ][d];
        float4 b1r = *(const float4*)&ks_r[k0+1][d];
        float4 b1i = *(const float4*)&ks_i[k0+1][d];
        CDOT4(s00r, s00i, a0r, a0i, b0r, b0i);
        CDOT4(s01r, s01i, a0r, a0i, b1r, b1i);
        CDOT4(s10r, s10i, a1r, a1i, b0r, b0i);
        CDOT4(s11r, s11i, a1r, a1i, b1r, b1i);
      }
      s00r *= 0.125f; s00i *= 0.125f; s01r *= 0.125f; s01i *= 0.125f;
      s10r *= 0.125f; s10i *= 0.125f; s11r *= 0.125f; s11i *= 0.125f;
      sc_r[q0  ][k0  ] = s00r; sc_i[q0  ][k0  ] = s00i;
      sc_m[q0  ][k0  ] = sqrtf(s00r*s00r + s00i*s00i);
      sc_r[q0  ][k0+1] = s01r; sc_i[q0  ][k0+1] = s01i;
      sc_m[q0  ][k0+1] = sqrtf(s01r*s01r + s01i*s01i);
      sc_r[q0+1][k0  ] = s10r; sc_i[q0+1][k0  ] = s10i;
      sc_m[q0+1][k0  ] = sqrtf(s10r*s10r + s10i*s10i);
      sc_r[q0+1][k0+1] = s11r; sc_i[q0+1][k0+1] = s11i;
      sc_m[q0+1][k0+1] = sqrtf(s11r*s11r + s11i*s11i);
    }
    __syncthreads();
#pragma unroll 8
    for (int k = 0; k < KT; ++k) {
      float sr = sc_r[rB][k], si = sc_i[rB][k], mg = sc_m[rB][k];
      mn = fminf(mn, mg); mx = fmaxf(mx, mg);
      float inv = 1.0f / mg;
      float ur = sr * inv, ui = si * inv;
      float vr[8], vi[8];
      *(float4*)&vr[0] = *(const float4*)&vs_r[k][dc];
      *(float4*)&vr[4] = *(const float4*)&vs_r[k][dc + 4];
      *(float4*)&vi[0] = *(const float4*)&vs_i[k][dc];
      *(float4*)&vi[4] = *(const float4*)&vs_i[k][dc + 4];
#pragma unroll
      for (int j = 0; j < 8; ++j) {
        Ar[j] += sr * vr[j] - si * vi[j];
        Ai[j] += sr * vi[j] + si * vr[j];
        Ur[j] += ur * vr[j] - ui * vi[j];
        Ui[j] += ur * vi[j] + ui * vr[j];
      }
    }
  }
  float invspan = 1.0f / (mx - mn);
  float outr[8], outi[8];
#pragma unroll
  for (int j = 0; j < 8; ++j) {
    outr[j] = (Ar[j] - mn * Ur[j]) * invspan;
    outi[j] = (Ai[j] - mn * Ui[j]) * invspan;
  }
  size_t o = base + (size_t)(qt2 * QT + rB) * D + dc;
  *(float4*)(gout + o)            = *(float4*)&outr[0];
  *(float4*)(gout + o + 4)        = *(float4*)&outr[4];
  *(float4*)(gout + HALF + o)     = *(float4*)&outi[0];
  *(float4*)(gout + HALF + o + 4) = *(float4*)&outi[4];
}

extern "C" void kernel_launch(void* const* d_in, const int* in_sizes, int n_in,
                              void* d_out, int out_size, void* d_ws, size_t ws_size,
                              hipStream_t stream) {
  if (ws_size >= WS_NEED) {
    prepass_kernel<<<dim3(BH * 32), 256, 0, stream>>>(
        (const float*)d_in[2], (const float*)d_in[3],
        (const float*)d_in[4], (const float*)d_in[5], (ushort_t*)d_ws);
    cvattn_mfma<<<dim3(S / 64, BH), 256, 0, stream>>>(
        (const float*)d_in[0], (const float*)d_in[1],
        (const ushort_t*)d_ws, (float*)d_out);
  } else {
    cvattn_fallback<<<dim3(S / QT, BH), 256, 0, stream>>>(
        (const float*)d_in[0], (const float*)d_in[1],
        (const float*)d_in[2], (const float*)d_in[3],
        (const float*)d_in[4], (const float*)d_in[5], (float*)d_out);
  }
}